// Round 11
// baseline (167.068 us; speedup 1.0000x reference)
//
#include <hip/hip_runtime.h>
#include <hip/hip_bf16.h>

#define B_   64
#define S_   2048
#define H_   256
#define H3_  768
#define K_   512            // 2H (static+dynamic)
#define MT   64             // M tile (positions per workgroup)
#define RSTR 1040           // LDS row stride in bytes (65 x 16B): 2-way banks, imm-foldable

typedef __attribute__((ext_vector_type(8))) short  bf16x8;
typedef __attribute__((ext_vector_type(4))) float  f32x4;

__device__ __forceinline__ uint pkbf2(float a, float b) {
    float2 f = make_float2(a, b);
    __hip_bfloat162 h = __float22bfloat162_rn(f);   // v_cvt_pk_bf16_f32
    return *reinterpret_cast<uint*>(&h);
}

// ---------------- kernel 1: pack W[:, 0:512] to bf16 in FRAGMENT order.
// Layout: [ot(48)][ks(16)][lane(64)][j(8)]
//   o = ot*16 + (lane&15), k = ks*32 + (lane>>4)*8 + j
__global__ void pack_w(const float* __restrict__ W, short* __restrict__ wpk) {
    int t = blockIdx.x * 256 + threadIdx.x;       // over 48*16*64
    if (t >= 48 * 16 * 64) return;
    int lane = t & 63;
    int ks   = (t >> 6) & 15;
    int ot   = t >> 10;
    int o  = ot * 16 + (lane & 15);
    int kb = ks * 32 + (lane >> 4) * 8;
    const float* src = W + (size_t)o * H3_ + kb;
    float4 a = ((const float4*)src)[0];
    float4 b = ((const float4*)src)[1];
    uint4 pk;
    pk.x = pkbf2(a.x, a.y);
    pk.y = pkbf2(a.z, a.w);
    pk.z = pkbf2(b.x, b.y);
    pk.w = pkbf2(b.z, b.w);
    *(uint4*)(wpk + (size_t)t * 8) = pk;
}

// ---------------- kernel 2: bias[b,o] = sum_k W[o,512+k]*dec[b,k]; block 192: vsum
__global__ void bias_k(const float* __restrict__ W, const float* __restrict__ dec,
                       const float* __restrict__ v, float* __restrict__ bias,
                       float* __restrict__ vsum) {
    if (blockIdx.x == 192) {                      // reduce sum(v) with one wave
        if (threadIdx.x < 64) {
            float s = 0.f;
#pragma unroll
            for (int i = 0; i < 12; ++i) s += v[threadIdx.x + i * 64];
#pragma unroll
            for (int off = 32; off >= 1; off >>= 1) s += __shfl_xor(s, off);
            if (threadIdx.x == 0) vsum[0] = s;
        }
        return;
    }
    int idx = blockIdx.x * 256 + threadIdx.x;     // over 64*768
    int b = idx / H3_;
    int o = idx - b * H3_;
    const float4* wr = (const float4*)(W + (size_t)o * H3_ + 2 * H_);
    const float4* dv = (const float4*)(dec + (size_t)b * H_);
    float s = 0.f;
#pragma unroll 8
    for (int k = 0; k < H_ / 4; ++k) {
        float4 a = wr[k], d = dv[k];
        s += a.x * d.x + a.y * d.y + a.z * d.z + a.w * d.w;
    }
    bias[idx] = s;
}

// ---------------- kernel 3: fused score GEMM.
// 512 threads (8 waves), single 65 KB LDS tile -> 2 blocks/CU = 4 waves/SIMD.
// Wave covers cols wave*96 + p*48 + ni*16 (p=0..1, ni=0..2), B 1-ks lookahead.
// scores[pos] = vsum + sum_o (-2 v[o]) * rcp(exp2(C1*h[pos,o]) + 1)
__global__ __launch_bounds__(512, 4)
void score_k(const float* __restrict__ stat, const float* __restrict__ dyn,
             const short* __restrict__ wpk, const float* __restrict__ bias,
             const float* __restrict__ v, const float* __restrict__ vsum,
             float* __restrict__ scores) {
    __shared__ char  aT[MT * RSTR];          // 65 KB, pad-1040 layout
    __shared__ float sred[8][MT];            // 2 KB

    const int tid  = threadIdx.x;
    const int pos0 = blockIdx.x * MT;
    const int bidx = pos0 >> 11;             // /2048 ; tile never crosses b

    const int wave = tid >> 6;
    const int lane = tid & 63;
    const int lr = lane & 15;                // A: row-in-16 ; B/C: col-in-16
    const int lg = lane >> 4;                // k-group (8 elems each)

    const short* wbase = wpk + (size_t)lane * 8;   // + ot*8192 + ks*512

    // preload pass-0 ks-0 B fragments: latency hides under the staging phase
    bf16x8 bcur[3];
#pragma unroll
    for (int ni = 0; ni < 3; ++ni)
        bcur[ni] = *(const bf16x8*)(wbase + (size_t)(wave * 6 + ni) * 8192);

    // ---- stage A: 64 rows x 512 k; per thread 8 units of 8 floats.
    // unit u: row = u*8 + wave-in-block-row, col fixed = lane*8 -> coalesced 2KB/wave
    {
        const int kcol = lane * 8;
        const float* srcbase = (kcol < 256) ? (stat + kcol) : (dyn + (kcol - 256));
#pragma unroll
        for (int bat = 0; bat < 2; ++bat) {
            float4 f0[4], f1[4];
#pragma unroll
            for (int u = 0; u < 4; ++u) {
                int row = (bat * 4 + u) * 8 + wave;
                const float4* p = (const float4*)(srcbase + (size_t)(pos0 + row) * H_);
                f0[u] = p[0];
                f1[u] = p[1];
            }
#pragma unroll
            for (int u = 0; u < 4; ++u) {
                int row = (bat * 4 + u) * 8 + wave;
                uint4 pk;
                pk.x = pkbf2(f0[u].x, f0[u].y);
                pk.y = pkbf2(f0[u].z, f0[u].w);
                pk.z = pkbf2(f1[u].x, f1[u].y);
                pk.w = pkbf2(f1[u].z, f1[u].w);
                *(uint4*)(aT + row * RSTR + lane * 16) = pk;
            }
        }
    }
    __syncthreads();

    // single base address for A-fragment reads (imm offsets cover mi, ks window)
    const char* abase = aT + lr * RSTR + lg * 16;

    float sacc[4][4];
#pragma unroll
    for (int mi = 0; mi < 4; ++mi)
#pragma unroll
        for (int j = 0; j < 4; ++j) sacc[mi][j] = 0.f;

    const float C1 = 2.8853900817779268f;    // 2*log2(e)

    // 2 passes x (8 waves x 48 cols) = 768 cols
#pragma unroll
    for (int p = 0; p < 2; ++p) {
        const int obase = wave * 96 + p * 48;

        float bv[3], vv2[3];
#pragma unroll
        for (int ni = 0; ni < 3; ++ni) {
            int o = obase + ni * 16 + lr;
            bv[ni]  = bias[bidx * H3_ + o];
            vv2[ni] = -2.0f * v[o];
        }

        f32x4 acc[4][3];                               // [mi][ni], init = bias
#pragma unroll
        for (int mi = 0; mi < 4; ++mi)
#pragma unroll
            for (int ni = 0; ni < 3; ++ni) {
                f32x4 a = {bv[ni], bv[ni], bv[ni], bv[ni]};
                acc[mi][ni] = a;
            }

        const short* wp0 = wbase + (size_t)(wave * 6 + p * 3) * 8192;

#pragma unroll 4
        for (int ks = 0; ks < 16; ++ks) {
            // 1-step lookahead for B: consumption is far after issue
            const int ksn = (ks + 1) & 15;             // wrap reload, overwritten later
            bf16x8 bnx[3];
#pragma unroll
            for (int ni = 0; ni < 3; ++ni)
                bnx[ni] = *(const bf16x8*)(wp0 + ni * 8192 + ksn * 512);
            bf16x8 afr[4];
#pragma unroll
            for (int mi = 0; mi < 4; ++mi)
                afr[mi] = *(const bf16x8*)(abase + mi * 16 * RSTR + ks * 64);
            __builtin_amdgcn_s_setprio(1);
#pragma unroll
            for (int mi = 0; mi < 4; ++mi)
#pragma unroll
                for (int ni = 0; ni < 3; ++ni)
                    acc[mi][ni] = __builtin_amdgcn_mfma_f32_16x16x32_bf16(
                        afr[mi], bcur[ni], acc[mi][ni], 0, 0, 0);
            __builtin_amdgcn_s_setprio(0);
#pragma unroll
            for (int ni = 0; ni < 3; ++ni) bcur[ni] = bnx[ni];
        }

        // preload next pass's ks-0 B fragments; epilogue covers the latency
        if (p == 0) {
            const short* wpn = wbase + (size_t)(wave * 6 + 3) * 8192;
#pragma unroll
            for (int ni = 0; ni < 3; ++ni)
                bcur[ni] = *(const bf16x8*)(wpn + ni * 8192);
        }

        // epilogue: sacc += (-2 v) * rcp(exp2(C1*h)+1)
#pragma unroll
        for (int ni = 0; ni < 3; ++ni)
#pragma unroll
            for (int mi = 0; mi < 4; ++mi)
#pragma unroll
                for (int j = 0; j < 4; ++j) {
                    float e = __builtin_amdgcn_exp2f(acc[mi][ni][j] * C1);
                    float r = __builtin_amdgcn_rcpf(e + 1.0f);
                    sacc[mi][j] = fmaf(vv2[ni], r, sacc[mi][j]);
                }
    }

    // reduce over the 16 column-lanes (lr); rows live at mi*16 + lg*4 + j
#pragma unroll
    for (int mi = 0; mi < 4; ++mi)
#pragma unroll
        for (int j = 0; j < 4; ++j) {
            float x = sacc[mi][j];
            x += __shfl_xor(x, 1);
            x += __shfl_xor(x, 2);
            x += __shfl_xor(x, 4);
            x += __shfl_xor(x, 8);
            sacc[mi][j] = x;
        }
    if (lr == 0) {
#pragma unroll
        for (int mi = 0; mi < 4; ++mi)
#pragma unroll
            for (int j = 0; j < 4; ++j)
                sred[wave][mi * 16 + lg * 4 + j] = sacc[mi][j];
    }
    __syncthreads();
    if (tid < MT) {
        float s = vsum[0];
#pragma unroll
        for (int w = 0; w < 8; ++w) s += sred[w][tid];
        scores[pos0 + tid] = s;
    }
}

// ---------------- kernel 4: softmax over S=2048 per b, in place on d_out
__global__ void softmax_k(float* __restrict__ out) {
    const int b = blockIdx.x;
    float* row = out + (size_t)b * S_;
    const int tid  = threadIdx.x;          // 256
    const int wave = tid >> 6;
    const int lane = tid & 63;

    float vals[8];
    float m = -1e30f;
#pragma unroll
    for (int i = 0; i < 8; ++i) {
        vals[i] = row[tid + i * 256];
        m = fmaxf(m, vals[i]);
    }
#pragma unroll
    for (int off = 32; off >= 1; off >>= 1) m = fmaxf(m, __shfl_xor(m, off));
    __shared__ float redm[4];
    __shared__ float reds[4];
    if (lane == 0) redm[wave] = m;
    __syncthreads();
    m = fmaxf(fmaxf(redm[0], redm[1]), fmaxf(redm[2], redm[3]));

    float s = 0.f;
#pragma unroll
    for (int i = 0; i < 8; ++i) {
        vals[i] = __expf(vals[i] - m);
        s += vals[i];
    }
#pragma unroll
    for (int off = 32; off >= 1; off >>= 1) s += __shfl_xor(s, off);
    if (lane == 0) reds[wave] = s;
    __syncthreads();
    s = reds[0] + reds[1] + reds[2] + reds[3];
    float inv = 1.0f / s;
#pragma unroll
    for (int i = 0; i < 8; ++i) row[tid + i * 256] = vals[i] * inv;
}

extern "C" void kernel_launch(void* const* d_in, const int* in_sizes, int n_in,
                              void* d_out, int out_size, void* d_ws, size_t ws_size,
                              hipStream_t stream) {
    const float* stat = (const float*)d_in[0];   // [64,2048,256]
    const float* dyn  = (const float*)d_in[1];   // [64,2048,256]
    const float* dec  = (const float*)d_in[2];   // [64,256]
    const float* v    = (const float*)d_in[3];   // [1,768]
    const float* W    = (const float*)d_in[4];   // [768,768]
    float* out = (float*)d_out;                  // [64,2048]

    short* wpk  = (short*)d_ws;                                 // 786432 B
    float* bias = (float*)((char*)d_ws + (size_t)H3_ * K_ * 2); // 196608 B
    float* vsum = bias + B_ * H3_;                              // 4 B

    pack_w <<<(48 * 16 * 64 + 255) / 256, 256, 0, stream>>>(W, wpk);
    bias_k <<<193, 256, 0, stream>>>(W, dec, v, bias, vsum);
    score_k<<<(B_ * S_) / MT, 512, 0, stream>>>(stat, dyn, wpk, bias, v, vsum, out);
    softmax_k<<<B_, 256, 0, stream>>>(out);
}

// Round 12
// 158.129 us; speedup vs baseline: 1.0565x; 1.0565x over previous
//
#include <hip/hip_runtime.h>
#include <hip/hip_bf16.h>

#define B_   64
#define S_   2048
#define H_   256
#define H3_  768
#define K_   512            // 2H (static+dynamic)
#define MT   64             // M tile (positions per workgroup)
#define RSTR 1040           // LDS row stride in bytes (65 x 16B): 2-way banks, imm-foldable

typedef __attribute__((ext_vector_type(8))) short  bf16x8;
typedef __attribute__((ext_vector_type(4))) float  f32x4;

__device__ __forceinline__ uint pkbf2(float a, float b) {
    float2 f = make_float2(a, b);
    __hip_bfloat162 h = __float22bfloat162_rn(f);   // v_cvt_pk_bf16_f32
    return *reinterpret_cast<uint*>(&h);
}

// ---------------- kernel 1: pack W[:, 0:512] to bf16 in FRAGMENT order.
// Layout: [ot(48)][ks(16)][lane(64)][j(8)]
//   o = ot*16 + (lane&15), k = ks*32 + (lane>>4)*8 + j
__global__ void pack_w(const float* __restrict__ W, short* __restrict__ wpk) {
    int t = blockIdx.x * 256 + threadIdx.x;       // over 48*16*64
    if (t >= 48 * 16 * 64) return;
    int lane = t & 63;
    int ks   = (t >> 6) & 15;
    int ot   = t >> 10;
    int o  = ot * 16 + (lane & 15);
    int kb = ks * 32 + (lane >> 4) * 8;
    const float* src = W + (size_t)o * H3_ + kb;
    float4 a = ((const float4*)src)[0];
    float4 b = ((const float4*)src)[1];
    uint4 pk;
    pk.x = pkbf2(a.x, a.y);
    pk.y = pkbf2(a.z, a.w);
    pk.z = pkbf2(b.x, b.y);
    pk.w = pkbf2(b.z, b.w);
    *(uint4*)(wpk + (size_t)t * 8) = pk;
}

// ---------------- kernel 2: bias[b,o] = sum_k W[o,512+k]*dec[b,k]; block 192: vsum
__global__ void bias_k(const float* __restrict__ W, const float* __restrict__ dec,
                       const float* __restrict__ v, float* __restrict__ bias,
                       float* __restrict__ vsum) {
    if (blockIdx.x == 192) {                      // reduce sum(v) with one wave
        if (threadIdx.x < 64) {
            float s = 0.f;
#pragma unroll
            for (int i = 0; i < 12; ++i) s += v[threadIdx.x + i * 64];
#pragma unroll
            for (int off = 32; off >= 1; off >>= 1) s += __shfl_xor(s, off);
            if (threadIdx.x == 0) vsum[0] = s;
        }
        return;
    }
    int idx = blockIdx.x * 256 + threadIdx.x;     // over 64*768
    int b = idx / H3_;
    int o = idx - b * H3_;
    const float4* wr = (const float4*)(W + (size_t)o * H3_ + 2 * H_);
    const float4* dv = (const float4*)(dec + (size_t)b * H_);
    float s = 0.f;
#pragma unroll 8
    for (int k = 0; k < H_ / 4; ++k) {
        float4 a = wr[k], d = dv[k];
        s += a.x * d.x + a.y * d.y + a.z * d.z + a.w * d.w;
    }
    bias[idx] = s;
}

// ---------------- kernel 3: fused score GEMM.
// 512 threads (8 waves), single 65 KB LDS tile -> 2 blocks/CU = 4 waves/SIMD.
// Wave covers cols wave*96 + p*48 + ni*16 (p=0..1, ni=0..2), B 1-ks lookahead.
// scores[pos] = vsum + sum_o (-2 v[o]) * rcp(exp2(C1*h[pos,o]) + 1)
// launch_bounds(512,2): VGPR cap 128 (16 waves/CU); live set ~124 fits, no spill.
__global__ __launch_bounds__(512, 2)
void score_k(const float* __restrict__ stat, const float* __restrict__ dyn,
             const short* __restrict__ wpk, const float* __restrict__ bias,
             const float* __restrict__ v, const float* __restrict__ vsum,
             float* __restrict__ scores) {
    __shared__ char  aT[MT * RSTR];          // 65 KB, pad-1040 layout
    __shared__ float sred[8][MT];            // 2 KB

    const int tid  = threadIdx.x;
    const int pos0 = blockIdx.x * MT;
    const int bidx = pos0 >> 11;             // /2048 ; tile never crosses b

    const int wave = tid >> 6;
    const int lane = tid & 63;
    const int lr = lane & 15;                // A: row-in-16 ; B/C: col-in-16
    const int lg = lane >> 4;                // k-group (8 elems each)

    const short* wbase = wpk + (size_t)lane * 8;   // + ot*8192 + ks*512

    // preload pass-0 ks-0 B fragments: latency hides under the staging phase
    bf16x8 bcur[3];
#pragma unroll
    for (int ni = 0; ni < 3; ++ni)
        bcur[ni] = *(const bf16x8*)(wbase + (size_t)(wave * 6 + ni) * 8192);

    // ---- stage A: 64 rows x 512 k; per thread 8 units of 8 floats.
    // unit u: row = u*8 + wave, col fixed = lane*8 -> coalesced 2KB/wave
    {
        const int kcol = lane * 8;
        const float* srcbase = (kcol < 256) ? (stat + kcol) : (dyn + (kcol - 256));
#pragma unroll
        for (int bat = 0; bat < 2; ++bat) {
            float4 f0[4], f1[4];
#pragma unroll
            for (int u = 0; u < 4; ++u) {
                int row = (bat * 4 + u) * 8 + wave;
                const float4* p = (const float4*)(srcbase + (size_t)(pos0 + row) * H_);
                f0[u] = p[0];
                f1[u] = p[1];
            }
#pragma unroll
            for (int u = 0; u < 4; ++u) {
                int row = (bat * 4 + u) * 8 + wave;
                uint4 pk;
                pk.x = pkbf2(f0[u].x, f0[u].y);
                pk.y = pkbf2(f0[u].z, f0[u].w);
                pk.z = pkbf2(f1[u].x, f1[u].y);
                pk.w = pkbf2(f1[u].z, f1[u].w);
                *(uint4*)(aT + row * RSTR + lane * 16) = pk;
            }
        }
    }
    __syncthreads();

    // single base address for A-fragment reads (imm offsets cover mi, ks window)
    const char* abase = aT + lr * RSTR + lg * 16;

    float sacc[4][4];
#pragma unroll
    for (int mi = 0; mi < 4; ++mi)
#pragma unroll
        for (int j = 0; j < 4; ++j) sacc[mi][j] = 0.f;

    const float C1 = 2.8853900817779268f;    // 2*log2(e)

    // 2 passes x (8 waves x 48 cols) = 768 cols
#pragma unroll
    for (int p = 0; p < 2; ++p) {
        const int obase = wave * 96 + p * 48;

        float bv[3], vv2[3];
#pragma unroll
        for (int ni = 0; ni < 3; ++ni) {
            int o = obase + ni * 16 + lr;
            bv[ni]  = bias[bidx * H3_ + o];
            vv2[ni] = -2.0f * v[o];
        }

        f32x4 acc[4][3];                               // [mi][ni], init = bias
#pragma unroll
        for (int mi = 0; mi < 4; ++mi)
#pragma unroll
            for (int ni = 0; ni < 3; ++ni) {
                f32x4 a = {bv[ni], bv[ni], bv[ni], bv[ni]};
                acc[mi][ni] = a;
            }

        const short* wp0 = wbase + (size_t)(wave * 6 + p * 3) * 8192;

#pragma unroll 4
        for (int ks = 0; ks < 16; ++ks) {
            // 1-step lookahead for B: consumption is far after issue
            const int ksn = (ks + 1) & 15;             // wrap reload, overwritten later
            bf16x8 bnx[3];
#pragma unroll
            for (int ni = 0; ni < 3; ++ni)
                bnx[ni] = *(const bf16x8*)(wp0 + ni * 8192 + ksn * 512);
            bf16x8 afr[4];
#pragma unroll
            for (int mi = 0; mi < 4; ++mi)
                afr[mi] = *(const bf16x8*)(abase + mi * 16 * RSTR + ks * 64);
            __builtin_amdgcn_s_setprio(1);
#pragma unroll
            for (int mi = 0; mi < 4; ++mi)
#pragma unroll
                for (int ni = 0; ni < 3; ++ni)
                    acc[mi][ni] = __builtin_amdgcn_mfma_f32_16x16x32_bf16(
                        afr[mi], bcur[ni], acc[mi][ni], 0, 0, 0);
            __builtin_amdgcn_s_setprio(0);
#pragma unroll
            for (int ni = 0; ni < 3; ++ni) bcur[ni] = bnx[ni];
        }

        // preload next pass's ks-0 B fragments; epilogue covers the latency
        if (p == 0) {
            const short* wpn = wbase + (size_t)(wave * 6 + 3) * 8192;
#pragma unroll
            for (int ni = 0; ni < 3; ++ni)
                bcur[ni] = *(const bf16x8*)(wpn + ni * 8192);
        }

        // epilogue: sacc += (-2 v) * rcp(exp2(C1*h)+1)
#pragma unroll
        for (int ni = 0; ni < 3; ++ni)
#pragma unroll
            for (int mi = 0; mi < 4; ++mi)
#pragma unroll
                for (int j = 0; j < 4; ++j) {
                    float e = __builtin_amdgcn_exp2f(acc[mi][ni][j] * C1);
                    float r = __builtin_amdgcn_rcpf(e + 1.0f);
                    sacc[mi][j] = fmaf(vv2[ni], r, sacc[mi][j]);
                }
    }

    // reduce over the 16 column-lanes (lr); rows live at mi*16 + lg*4 + j
#pragma unroll
    for (int mi = 0; mi < 4; ++mi)
#pragma unroll
        for (int j = 0; j < 4; ++j) {
            float x = sacc[mi][j];
            x += __shfl_xor(x, 1);
            x += __shfl_xor(x, 2);
            x += __shfl_xor(x, 4);
            x += __shfl_xor(x, 8);
            sacc[mi][j] = x;
        }
    if (lr == 0) {
#pragma unroll
        for (int mi = 0; mi < 4; ++mi)
#pragma unroll
            for (int j = 0; j < 4; ++j)
                sred[wave][mi * 16 + lg * 4 + j] = sacc[mi][j];
    }
    __syncthreads();
    if (tid < MT) {
        float s = vsum[0];
#pragma unroll
        for (int w = 0; w < 8; ++w) s += sred[w][tid];
        scores[pos0 + tid] = s;
    }
}

// ---------------- kernel 4: softmax over S=2048 per b, in place on d_out
__global__ void softmax_k(float* __restrict__ out) {
    const int b = blockIdx.x;
    float* row = out + (size_t)b * S_;
    const int tid  = threadIdx.x;          // 256
    const int wave = tid >> 6;
    const int lane = tid & 63;

    float vals[8];
    float m = -1e30f;
#pragma unroll
    for (int i = 0; i < 8; ++i) {
        vals[i] = row[tid + i * 256];
        m = fmaxf(m, vals[i]);
    }
#pragma unroll
    for (int off = 32; off >= 1; off >>= 1) m = fmaxf(m, __shfl_xor(m, off));
    __shared__ float redm[4];
    __shared__ float reds[4];
    if (lane == 0) redm[wave] = m;
    __syncthreads();
    m = fmaxf(fmaxf(redm[0], redm[1]), fmaxf(redm[2], redm[3]));

    float s = 0.f;
#pragma unroll
    for (int i = 0; i < 8; ++i) {
        vals[i] = __expf(vals[i] - m);
        s += vals[i];
    }
#pragma unroll
    for (int off = 32; off >= 1; off >>= 1) s += __shfl_xor(s, off);
    if (lane == 0) reds[wave] = s;
    __syncthreads();
    s = reds[0] + reds[1] + reds[2] + reds[3];
    float inv = 1.0f / s;
#pragma unroll
    for (int i = 0; i < 8; ++i) row[tid + i * 256] = vals[i] * inv;
}

extern "C" void kernel_launch(void* const* d_in, const int* in_sizes, int n_in,
                              void* d_out, int out_size, void* d_ws, size_t ws_size,
                              hipStream_t stream) {
    const float* stat = (const float*)d_in[0];   // [64,2048,256]
    const float* dyn  = (const float*)d_in[1];   // [64,2048,256]
    const float* dec  = (const float*)d_in[2];   // [64,256]
    const float* v    = (const float*)d_in[3];   // [1,768]
    const float* W    = (const float*)d_in[4];   // [768,768]
    float* out = (float*)d_out;                  // [64,2048]

    short* wpk  = (short*)d_ws;                                 // 786432 B
    float* bias = (float*)((char*)d_ws + (size_t)H3_ * K_ * 2); // 196608 B
    float* vsum = bias + B_ * H3_;                              // 4 B

    pack_w <<<(48 * 16 * 64 + 255) / 256, 256, 0, stream>>>(W, wpk);
    bias_k <<<193, 256, 0, stream>>>(W, dec, v, bias, vsum);
    score_k<<<(B_ * S_) / MT, 512, 0, stream>>>(stat, dyn, wpk, bias, v, vsum, out);
    softmax_k<<<B_, 256, 0, stream>>>(out);
}